// Round 3
// baseline (388.705 us; speedup 1.0000x reference)
//
#include <hip/hip_runtime.h>

typedef __attribute__((ext_vector_type(8))) short bf16x8;
typedef __attribute__((ext_vector_type(8))) unsigned short u16x8;
typedef __attribute__((ext_vector_type(4))) float f32x4;
typedef unsigned short u16t;

#define MFMA16(a, b, c) __builtin_amdgcn_mfma_f32_16x16x32_bf16((a), (b), (c), 0, 0, 0)
#define GLDS16(gp, lp)                                                        \
  __builtin_amdgcn_global_load_lds(                                           \
      (__attribute__((address_space(1))) void*)(gp),                          \
      (__attribute__((address_space(3))) void*)(lp), 16, 0, 0)

static constexpr float L2E = 1.44269504f;   // log2(e)
static constexpr float MASKV = -1.0e30f;    // finite mask sentinel (no inf paths)
static constexpr float MASKTH = -5.0e29f;   // "is real score" threshold

__device__ __forceinline__ u16t f2b(float f) {
  unsigned u = __builtin_bit_cast(unsigned, f);
  u = u + 0x7fffu + ((u >> 16) & 1u); // RNE
  return (u16t)(u >> 16);
}

// ---------------------------------------------------------------------------
// fp32 -> bf16 conversion of x and the 4 weight matrices, one fused launch.
// x: 8.4M elems (4096 blocks); each W: 1M elems (512 blocks). 8 elems/thread.
// ---------------------------------------------------------------------------
__global__ void cvt5(const float* __restrict__ x, const float* __restrict__ wq,
                     const float* __restrict__ wk, const float* __restrict__ wv,
                     const float* __restrict__ wo, u16t* __restrict__ xb,
                     u16t* __restrict__ wqb, u16t* __restrict__ wkb,
                     u16t* __restrict__ wvb, u16t* __restrict__ wob) {
  const int bid = blockIdx.x;
  const float* src; u16t* dst; int gb;
  if (bid < 4096)      { src = x;  dst = xb;  gb = bid; }
  else if (bid < 4608) { src = wq; dst = wqb; gb = bid - 4096; }
  else if (bid < 5120) { src = wk; dst = wkb; gb = bid - 4608; }
  else if (bid < 5632) { src = wv; dst = wvb; gb = bid - 5120; }
  else                 { src = wo; dst = wob; gb = bid - 5632; }
  const size_t i = (size_t)gb * 256 + threadIdx.x; // 8-elem group index
  const float4 a = ((const float4*)src)[2 * i];
  const float4 b = ((const float4*)src)[2 * i + 1];
  u16x8 r;
  r[0] = f2b(a.x); r[1] = f2b(a.y); r[2] = f2b(a.z); r[3] = f2b(a.w);
  r[4] = f2b(b.x); r[5] = f2b(b.y); r[6] = f2b(b.z); r[7] = f2b(b.w);
  *(u16x8*)&dst[8 * i] = r;
}

// ---------------------------------------------------------------------------
// GEMM core: C[128x128 block] = A[M,K] @ W[N,K]^T ; bf16 in (ws), fp32 MFMA
// accumulate, fp32 bias. m97 structure: BK=32, 4 waves 2x2, 4x4 MFMA tiles.
// ---------------------------------------------------------------------------
__global__ void gemm_qkv(const u16t* __restrict__ X,
                         const u16t* __restrict__ Wq, const u16t* __restrict__ Wk,
                         const u16t* __restrict__ Wv,
                         const float* __restrict__ bq, const float* __restrict__ bk,
                         const float* __restrict__ bv,
                         u16t* __restrict__ Qo, u16t* __restrict__ Ko,
                         u16t* __restrict__ Vo) {
  __shared__ __align__(16) u16t As[128 * 32];
  __shared__ __align__(16) u16t Bs[128 * 32];
  const int t = threadIdx.x, lane = t & 63, w = t >> 6;
  const int wr = w >> 1, wc = w & 1, m = lane & 15, quad = lane >> 4;
  const int rowBase = blockIdx.y * 128, colBase = blockIdx.x * 128;
  const int z = blockIdx.z;
  const u16t* W = (z == 0) ? Wq : ((z == 1) ? Wk : Wv);
  const float* bias = (z == 0) ? bq : ((z == 1) ? bk : bv);
  u16t* Out = (z == 0) ? Qo : ((z == 1) ? Ko : Vo);

  f32x4 acc[4][4];
#pragma unroll
  for (int i = 0; i < 4; i++)
#pragma unroll
    for (int j = 0; j < 4; j++) acc[i][j] = (f32x4){0.f, 0.f, 0.f, 0.f};

  const int lr = lane >> 2, lc = (lane & 3) * 8;
  for (int kt = 0; kt < 32; ++kt) {
#pragma unroll
    for (int i = 0; i < 2; ++i) {
      const int r0 = i * 64 + w * 16; // wave-uniform LDS region base
      GLDS16(&X[(size_t)(rowBase + r0 + lr) * 1024 + kt * 32 + lc], &As[r0 * 32]);
      GLDS16(&W[(size_t)(colBase + r0 + lr) * 1024 + kt * 32 + lc], &Bs[r0 * 32]);
    }
    __syncthreads();
    bf16x8 af[4], bfr[4];
#pragma unroll
    for (int i = 0; i < 4; i++)
      af[i] = *(const bf16x8*)&As[(wr * 64 + i * 16 + m) * 32 + quad * 8];
#pragma unroll
    for (int j = 0; j < 4; j++)
      bfr[j] = *(const bf16x8*)&Bs[(wc * 64 + j * 16 + m) * 32 + quad * 8];
#pragma unroll
    for (int i = 0; i < 4; i++)
#pragma unroll
      for (int j = 0; j < 4; j++) acc[i][j] = MFMA16(af[i], bfr[j], acc[i][j]);
    __syncthreads();
  }

  // epilogue: write [B,H,S,HD]  (row = b*1024+s ; col = h*64+hd), add bias
#pragma unroll
  for (int j = 0; j < 4; j++) {
    const int col = colBase + wc * 64 + j * 16 + m;
    const float bv_ = bias[col];
    const int h = col >> 6, hd = col & 63;
#pragma unroll
    for (int i = 0; i < 4; i++) {
#pragma unroll
      for (int r = 0; r < 4; r++) {
        const int row = rowBase + wr * 64 + i * 16 + quad * 4 + r;
        const int b_ = row >> 10, s_ = row & 1023;
        const size_t oi = (((size_t)b_ * 16 + h) * 1024 + s_) * 64 + hd;
        Out[oi] = f2b(acc[i][j][r] + bv_);
      }
    }
  }
}

__global__ void gemm_o(const u16t* __restrict__ A, const u16t* __restrict__ W,
                       const float* __restrict__ bias, float* __restrict__ Out) {
  __shared__ __align__(16) u16t As[128 * 32];
  __shared__ __align__(16) u16t Bs[128 * 32];
  const int t = threadIdx.x, lane = t & 63, w = t >> 6;
  const int wr = w >> 1, wc = w & 1, m = lane & 15, quad = lane >> 4;
  const int rowBase = blockIdx.y * 128, colBase = blockIdx.x * 128;

  f32x4 acc[4][4];
#pragma unroll
  for (int i = 0; i < 4; i++)
#pragma unroll
    for (int j = 0; j < 4; j++) acc[i][j] = (f32x4){0.f, 0.f, 0.f, 0.f};

  const int lr = lane >> 2, lc = (lane & 3) * 8;
  for (int kt = 0; kt < 32; ++kt) {
#pragma unroll
    for (int i = 0; i < 2; ++i) {
      const int r0 = i * 64 + w * 16;
      GLDS16(&A[(size_t)(rowBase + r0 + lr) * 1024 + kt * 32 + lc], &As[r0 * 32]);
      GLDS16(&W[(size_t)(colBase + r0 + lr) * 1024 + kt * 32 + lc], &Bs[r0 * 32]);
    }
    __syncthreads();
    bf16x8 af[4], bfr[4];
#pragma unroll
    for (int i = 0; i < 4; i++)
      af[i] = *(const bf16x8*)&As[(wr * 64 + i * 16 + m) * 32 + quad * 8];
#pragma unroll
    for (int j = 0; j < 4; j++)
      bfr[j] = *(const bf16x8*)&Bs[(wc * 64 + j * 16 + m) * 32 + quad * 8];
#pragma unroll
    for (int i = 0; i < 4; i++)
#pragma unroll
      for (int j = 0; j < 4; j++) acc[i][j] = MFMA16(af[i], bfr[j], acc[i][j]);
    __syncthreads();
  }

#pragma unroll
  for (int j = 0; j < 4; j++) {
    const int col = colBase + wc * 64 + j * 16 + m;
    const float bv_ = bias[col];
#pragma unroll
    for (int i = 0; i < 4; i++) {
#pragma unroll
      for (int r = 0; r < 4; r++) {
        const int row = rowBase + wr * 64 + i * 16 + quad * 4 + r;
        Out[(size_t)row * 1024 + col] = acc[i][j][r] + bv_;
      }
    }
  }
}

// ---------------------------------------------------------------------------
// Flash attention: grid (S/64, H, B), 256 thr. Wave w owns q-rows
// [qt*64+w*16, +16). Online softmax fp32, finite by construction. P via
// per-wave LDS into A-layout; V staged transposed (stride 72: aligned,
// de-pow2 banks).
// ---------------------------------------------------------------------------
__global__ void attn(const u16t* __restrict__ Q, const u16t* __restrict__ K,
                     const u16t* __restrict__ V, const int* __restrict__ ids,
                     u16t* __restrict__ Oo) {
  constexpr int PSTR = 72;
  __shared__ __align__(16) u16t Vt[64 * PSTR];
  __shared__ __align__(16) u16t Ps[4][16 * PSTR];
  const int t = threadIdx.x, lane = t & 63, w = t >> 6;
  const int m = lane & 15, quad = lane >> 4;
  const int qt = blockIdx.x, h = blockIdx.y, b = blockIdx.z;
  const size_t hoff = ((size_t)b * 16 + h) * 1024 * 64;
  const int qbase = qt * 64 + w * 16;
  const int qrow0 = qbase + quad * 4; // + r

  const bf16x8 qf0 = *(const bf16x8*)&Q[hoff + (size_t)(qbase + m) * 64 + quad * 8];
  const bf16x8 qf1 = *(const bf16x8*)&Q[hoff + (size_t)(qbase + m) * 64 + 32 + quad * 8];

  float mi[4], li[4];
  f32x4 o[4];
#pragma unroll
  for (int r = 0; r < 4; r++) { mi[r] = MASKV; li[r] = 0.f; }
#pragma unroll
  for (int ot = 0; ot < 4; ot++) o[ot] = (f32x4){0.f, 0.f, 0.f, 0.f};

  const int idsb = b * 1024;

  for (int kt = 0; kt <= qt; ++kt) {
    __syncthreads(); // protect Vt from prior-iteration readers
    // stage V^T: Vt[hd][key]
#pragma unroll
    for (int it = 0; it < 2; ++it) {
      const int idx = t + it * 256;
      const int key = idx >> 3, hd0 = (idx & 7) * 8;
      const bf16x8 vv = *(const bf16x8*)&V[hoff + (size_t)(kt * 64 + key) * 64 + hd0];
#pragma unroll
      for (int j = 0; j < 8; j++) Vt[(hd0 + j) * PSTR + key] = (u16t)vv[j];
    }
    __syncthreads();

    // scores: 4 n-tiles of 16 keys
    f32x4 sc[4];
    float rowmax[4] = {MASKV, MASKV, MASKV, MASKV};
#pragma unroll
    for (int nt = 0; nt < 4; nt++) {
      const bool active = (kt * 64 + nt * 16) <= (qbase + 15); // wave-uniform
      if (active) {
        const int key = kt * 64 + nt * 16 + m;
        const bf16x8 k0 = *(const bf16x8*)&K[hoff + (size_t)key * 64 + quad * 8];
        const bf16x8 k1 = *(const bf16x8*)&K[hoff + (size_t)key * 64 + 32 + quad * 8];
        f32x4 c = (f32x4){0.f, 0.f, 0.f, 0.f};
        c = MFMA16(qf0, k0, c);
        c = MFMA16(qf1, k1, c);
        const bool pv = (ids[idsb + key] != 1);
#pragma unroll
        for (int r = 0; r < 4; r++) {
          const float s = (pv && key <= qrow0 + r) ? c[r] * 0.125f : MASKV;
          sc[nt][r] = s;
          rowmax[r] = fmaxf(rowmax[r], s);
        }
      } else {
#pragma unroll
        for (int r = 0; r < 4; r++) sc[nt][r] = MASKV;
      }
    }
    // row-max across the 16 cols (lanes of the quad)
#pragma unroll
    for (int r = 0; r < 4; r++) {
      float v_ = rowmax[r];
      v_ = fmaxf(v_, __shfl_xor(v_, 1));
      v_ = fmaxf(v_, __shfl_xor(v_, 2));
      v_ = fmaxf(v_, __shfl_xor(v_, 4));
      v_ = fmaxf(v_, __shfl_xor(v_, 8));
      rowmax[r] = v_;
    }
    float alpha[4], rsum[4];
#pragma unroll
    for (int r = 0; r < 4; r++) {
      const float mn = fmaxf(mi[r], rowmax[r]);
      alpha[r] = exp2f((mi[r] - mn) * L2E); // finite arg; underflows to 0
      mi[r] = mn;
      rsum[r] = 0.f;
    }
    // P = exp(s - m) for real scores, 0 for masked; bf16 to per-wave staging
#pragma unroll
    for (int nt = 0; nt < 4; nt++) {
#pragma unroll
      for (int r = 0; r < 4; r++) {
        const float p =
            (sc[nt][r] > MASKTH) ? exp2f((sc[nt][r] - mi[r]) * L2E) : 0.f;
        rsum[r] += p;
        Ps[w][(quad * 4 + r) * PSTR + nt * 16 + m] = f2b(p);
      }
    }
    // row-sum across cols, update l
#pragma unroll
    for (int r = 0; r < 4; r++) {
      float v_ = rsum[r];
      v_ += __shfl_xor(v_, 1);
      v_ += __shfl_xor(v_, 2);
      v_ += __shfl_xor(v_, 4);
      v_ += __shfl_xor(v_, 8);
      li[r] = li[r] * alpha[r] + v_;
    }
    // rescale O then accumulate P @ V
#pragma unroll
    for (int ot = 0; ot < 4; ot++)
#pragma unroll
      for (int r = 0; r < 4; r++) o[ot][r] *= alpha[r];

    const bf16x8 p0 = *(const bf16x8*)&Ps[w][m * PSTR + quad * 8];
    const bf16x8 p1 = *(const bf16x8*)&Ps[w][m * PSTR + 32 + quad * 8];
#pragma unroll
    for (int ot = 0; ot < 4; ot++) {
      const bf16x8 v0 = *(const bf16x8*)&Vt[(ot * 16 + m) * PSTR + quad * 8];
      const bf16x8 v1 = *(const bf16x8*)&Vt[(ot * 16 + m) * PSTR + 32 + quad * 8];
      o[ot] = MFMA16(p0, v0, o[ot]);
      o[ot] = MFMA16(p1, v1, o[ot]);
    }
  }

  // write attn output [B,S,D] with D-index = h*64 + hd (bf16, ws)
#pragma unroll
  for (int r = 0; r < 4; r++) {
    const float inv = li[r] > 1e-30f ? 1.f / li[r] : 0.f;
    const int q = qbase + quad * 4 + r;
#pragma unroll
    for (int ot = 0; ot < 4; ot++) {
      const int col = h * 64 + ot * 16 + m;
      Oo[((size_t)(b * 1024 + q)) * 1024 + col] = f2b(o[ot][r] * inv);
    }
  }
}

// ---------------------------------------------------------------------------
extern "C" void kernel_launch(void* const* d_in, const int* in_sizes, int n_in,
                              void* d_out, int out_size, void* d_ws, size_t ws_size,
                              hipStream_t stream) {
  const float* x  = (const float*)d_in[0];
  const int*   ids = (const int*)d_in[1];
  const float* Wq = (const float*)d_in[2];
  const float* bq = (const float*)d_in[3];
  const float* Wk = (const float*)d_in[4];
  const float* bk = (const float*)d_in[5];
  const float* Wv = (const float*)d_in[6];
  const float* bv = (const float*)d_in[7];
  const float* Wo = (const float*)d_in[8];
  const float* bo = (const float*)d_in[9];
  float* out = (float*)d_out;

  // ws layout (bf16 elems): XB 8.4M | WqB,WkB,WvB,WoB 1M each | Q,K,V 8.4M each
  // = 72 MiB. AO reuses XB (stream-ordered: gemm_qkv finishes before attn).
  u16t* XB  = (u16t*)d_ws;
  u16t* WqB = XB  + 8388608;
  u16t* WkB = WqB + 1048576;
  u16t* WvB = WkB + 1048576;
  u16t* WoB = WvB + 1048576;
  u16t* Qw  = WoB + 1048576;
  u16t* Kw  = Qw  + 8388608;
  u16t* Vw  = Kw  + 8388608;
  u16t* AO  = XB; // reuse after gemm_qkv consumed XB

  cvt5<<<6144, 256, 0, stream>>>(x, Wq, Wk, Wv, Wo, XB, WqB, WkB, WvB, WoB);
  gemm_qkv<<<dim3(8, 64, 3), 256, 0, stream>>>(XB, WqB, WkB, WvB, bq, bk, bv,
                                               Qw, Kw, Vw);
  attn<<<dim3(16, 16, 8), 256, 0, stream>>>(Qw, Kw, Vw, ids, AO);
  gemm_o<<<dim3(8, 64, 1), 256, 0, stream>>>(AO, WoB, bo, out);
}